// Round 2
// baseline (2154.991 us; speedup 1.0000x reference)
//
#include <hip/hip_runtime.h>

#define N_NODES 200000
#define N_EDGES 600000
#define N_GRAPHS 10000
#define F_NODE 32
#define HDIM 128
#define BN_EPS 1e-5f

// ---------------- zero fill (graph-capture-safe memset) ----------------
__global__ __launch_bounds__(256) void fill_zero_k(float* __restrict__ p, long long n)
{
    long long gid = (long long)blockIdx.x * blockDim.x + threadIdx.x;
    long long stride = (long long)gridDim.x * blockDim.x;
    for (long long i = gid; i < n; i += stride) p[i] = 0.f;
}

// ---------------- scatter-add: agg[dst] += h[src], feature dim D ----------------
template<int D>
__global__ __launch_bounds__(256) void scatter_add_k(
    const float* __restrict__ h, const int* __restrict__ src,
    const int* __restrict__ dst, float* __restrict__ agg)
{
    long long gid = (long long)blockIdx.x * blockDim.x + threadIdx.x;
    long long total = (long long)N_EDGES * D;
    if (gid >= total) return;
    int e = (int)(gid / D);
    int f = (int)(gid % D);
    int s = src[e], d = dst[e];
    atomicAdd(&agg[(long long)d * D + f], h[(long long)s * D + f]);
}

// ---------------- GEMM1 fused: out = relu(BN((x+agg) @ w1 + b1)) ----------------
// x, agg: [N_NODES, K]; w1: [K, 128]; out: [N_NODES, 128]
// Safe for out == agg (row-wise: rows staged to LDS before overwrite).
template<int K>
__global__ __launch_bounds__(256) void gemm_bn_relu_k(
    const float* __restrict__ x, const float* __restrict__ agg,
    const float* __restrict__ w1, const float* __restrict__ b1,
    const float* __restrict__ gamma, const float* __restrict__ beta,
    const float* __restrict__ rmean, const float* __restrict__ rvar,
    float* __restrict__ out)
{
    __shared__ float Ws[K * HDIM];
    __shared__ float Xs[4][K];
    for (int i = threadIdx.x; i < K * HDIM; i += 256) Ws[i] = w1[i];

    const int j  = threadIdx.x & 127;
    const int rg = threadIdx.x >> 7;   // 0 or 1: which row pair
    const float scale = gamma[j] * rsqrtf(rvar[j] + BN_EPS);
    const float shift = (b1[j] - rmean[j]) * scale + beta[j];
    __syncthreads();

    for (long long n0 = (long long)blockIdx.x * 4; n0 < N_NODES;
         n0 += (long long)gridDim.x * 4) {
        // stage 4 rows of (x + agg)
        for (int i = threadIdx.x; i < 4 * K; i += 256) {
            int rw = i / K, kk = i % K;
            long long nn = n0 + rw;
            Xs[rw][kk] = (nn < N_NODES) ? (x[nn * K + kk] + agg[nn * K + kk]) : 0.f;
        }
        __syncthreads();

        float acc0 = 0.f, acc1 = 0.f;
        const float* xr0 = &Xs[rg * 2][0];
        const float* xr1 = &Xs[rg * 2 + 1][0];
        #pragma unroll 8
        for (int k = 0; k < K; ++k) {
            float w = Ws[k * HDIM + j];
            acc0 += xr0[k] * w;
            acc1 += xr1[k] * w;
        }
        long long r0 = n0 + rg * 2, r1 = r0 + 1;
        if (r0 < N_NODES) out[r0 * HDIM + j] = fmaxf(acc0 * scale + shift, 0.f);
        if (r1 < N_NODES) out[r1 * HDIM + j] = fmaxf(acc1 * scale + shift, 0.f);
        __syncthreads();
    }
}

// ---------------- GEMM2 fused: out = relu(t @ w2 + b2) ----------------
// Safe for out == t (row-wise in-place).
__global__ __launch_bounds__(256) void gemm_relu_k(
    const float* __restrict__ t, const float* __restrict__ w2,
    const float* __restrict__ b2, float* __restrict__ out)
{
    __shared__ float Ws[HDIM * HDIM];
    __shared__ float Xs[4][HDIM];
    for (int i = threadIdx.x; i < HDIM * HDIM; i += 256) Ws[i] = w2[i];

    const int j  = threadIdx.x & 127;
    const int rg = threadIdx.x >> 7;
    const float bias = b2[j];
    __syncthreads();

    for (long long n0 = (long long)blockIdx.x * 4; n0 < N_NODES;
         n0 += (long long)gridDim.x * 4) {
        for (int i = threadIdx.x; i < 4 * HDIM; i += 256) {
            int rw = i >> 7, kk = i & 127;
            long long nn = n0 + rw;
            Xs[rw][kk] = (nn < N_NODES) ? t[nn * HDIM + kk] : 0.f;
        }
        __syncthreads();

        float acc0 = 0.f, acc1 = 0.f;
        const float* xr0 = &Xs[rg * 2][0];
        const float* xr1 = &Xs[rg * 2 + 1][0];
        #pragma unroll 8
        for (int k = 0; k < HDIM; ++k) {
            float w = Ws[k * HDIM + j];
            acc0 += xr0[k] * w;
            acc1 += xr1[k] * w;
        }
        long long r0 = n0 + rg * 2, r1 = r0 + 1;
        if (r0 < N_NODES) out[r0 * HDIM + j] = fmaxf(acc0 + bias, 0.f);
        if (r1 < N_NODES) out[r1 * HDIM + j] = fmaxf(acc1 + bias, 0.f);
        __syncthreads();
    }
}

// ---------------- pool: pooled[batch[n]] += h[n] (batch sorted -> strip reduce) ----
__global__ __launch_bounds__(256) void pool_add_k(
    const float* __restrict__ h, const int* __restrict__ batch,
    float* __restrict__ pooled)
{
    const int nStrips = (N_NODES + 7) / 8;
    long long gid = (long long)blockIdx.x * blockDim.x + threadIdx.x;
    long long total = (long long)nStrips * HDIM;
    if (gid >= total) return;
    int strip = (int)(gid >> 7);
    int j = (int)(gid & 127);
    int n0 = strip * 8;
    int nend = n0 + 8; if (nend > N_NODES) nend = N_NODES;
    int curb = batch[n0];
    float sum = 0.f;
    for (int n = n0; n < nend; ++n) {
        int b = batch[n];
        if (b != curb) {
            atomicAdd(&pooled[(long long)curb * HDIM + j], sum);
            curb = b; sum = 0.f;
        }
        sum += h[(long long)n * HDIM + j];
    }
    atomicAdd(&pooled[(long long)curb * HDIM + j], sum);
}

// ---------------- head: out[g] = relu(pooled[g] @ w_fc1 + b_fc1) @ w_fc2 + b_fc2 ----
__global__ __launch_bounds__(64) void fc_head_k(
    const float* __restrict__ pooled,
    const float* __restrict__ w_fc1, const float* __restrict__ b_fc1,
    const float* __restrict__ w_fc2, const float* __restrict__ b_fc2,
    float* __restrict__ out)
{
    int g = blockIdx.x;
    int j = threadIdx.x;   // 0..63
    __shared__ float p[HDIM];
    p[j]      = pooled[(long long)g * HDIM + j];
    p[j + 64] = pooled[(long long)g * HDIM + j + 64];
    __syncthreads();

    float acc = b_fc1[j];
    #pragma unroll 8
    for (int k = 0; k < HDIM; ++k) acc += p[k] * w_fc1[k * 64 + j];
    acc = fmaxf(acc, 0.f);

    float v = acc * w_fc2[j];
    #pragma unroll
    for (int off = 32; off > 0; off >>= 1) v += __shfl_down(v, off, 64);
    if (j == 0) out[g] = v + b_fc2[0];
}

extern "C" void kernel_launch(void* const* d_in, const int* in_sizes, int n_in,
                              void* d_out, int out_size, void* d_ws, size_t ws_size,
                              hipStream_t stream) {
    const float* x     = (const float*)d_in[0];
    const int*   ei    = (const int*)d_in[1];
    const int*   src   = ei;                // edge_index[0]
    const int*   dst   = ei + N_EDGES;      // edge_index[1]
    const int*   batch = (const int*)d_in[3];
    // per-layer params at indices 4 + 8*l : {w1,b1,gamma,beta,rmean,rvar,w2,b2}
    const float* L[3][8];
    for (int l = 0; l < 3; ++l)
        for (int p = 0; p < 8; ++p)
            L[l][p] = (const float*)d_in[4 + 8 * l + p];
    const float* w_fc1 = (const float*)d_in[30];
    const float* b_fc1 = (const float*)d_in[31];
    const float* w_fc2 = (const float*)d_in[32];
    const float* b_fc2 = (const float*)d_in[33];
    float* out = (float*)d_out;

    // workspace layout (floats): 2 rotating N x 128 buffers + pooled
    // total = 2*25.6M + 1.28M floats = ~210 MB
    const size_t NH = (size_t)N_NODES * HDIM;            // 25.6M
    float* buf0   = (float*)d_ws;
    float* buf1   = buf0 + NH;
    float* pooled = buf1 + NH;                           // [N_GRAPHS, H]

    const int GEMM_GRID = 2048;
    const int FILL_GRID = 1024;

    // ---------- layer 1 (K = 32): scatter x -> buf0(Nx32); gemm -> buf1 ----------
    fill_zero_k<<<FILL_GRID, 256, 0, stream>>>(buf0, (long long)N_NODES * F_NODE);
    {
        long long tot = (long long)N_EDGES * F_NODE;
        scatter_add_k<F_NODE><<<(int)((tot + 255) / 256), 256, 0, stream>>>(x, src, dst, buf0);
    }
    gemm_bn_relu_k<F_NODE><<<GEMM_GRID, 256, 0, stream>>>(
        x, buf0, L[0][0], L[0][1], L[0][2], L[0][3], L[0][4], L[0][5], buf1);
    gemm_relu_k<<<GEMM_GRID, 256, 0, stream>>>(buf1, L[0][6], L[0][7], buf1);  // in-place

    // ---------- layer 2: h=buf1; scatter -> buf0; gemms end in buf0 ----------
    fill_zero_k<<<FILL_GRID, 256, 0, stream>>>(buf0, (long long)NH);
    {
        long long tot = (long long)N_EDGES * HDIM;
        scatter_add_k<HDIM><<<(int)((tot + 255) / 256), 256, 0, stream>>>(buf1, src, dst, buf0);
    }
    gemm_bn_relu_k<HDIM><<<GEMM_GRID, 256, 0, stream>>>(
        buf1, buf0, L[1][0], L[1][1], L[1][2], L[1][3], L[1][4], L[1][5], buf0); // in-place over agg
    gemm_relu_k<<<GEMM_GRID, 256, 0, stream>>>(buf0, L[1][6], L[1][7], buf0);    // in-place

    // ---------- layer 3: h=buf0; scatter -> buf1; gemms end in buf1 ----------
    fill_zero_k<<<FILL_GRID, 256, 0, stream>>>(buf1, (long long)NH);
    {
        long long tot = (long long)N_EDGES * HDIM;
        scatter_add_k<HDIM><<<(int)((tot + 255) / 256), 256, 0, stream>>>(buf0, src, dst, buf1);
    }
    gemm_bn_relu_k<HDIM><<<GEMM_GRID, 256, 0, stream>>>(
        buf0, buf1, L[2][0], L[2][1], L[2][2], L[2][3], L[2][4], L[2][5], buf1); // in-place over agg
    gemm_relu_k<<<GEMM_GRID, 256, 0, stream>>>(buf1, L[2][6], L[2][7], buf1);    // in-place

    // ---------- pool + head ----------
    fill_zero_k<<<FILL_GRID, 256, 0, stream>>>(pooled, (long long)N_GRAPHS * HDIM);
    {
        const int nStrips = (N_NODES + 7) / 8;
        long long tot = (long long)nStrips * HDIM;
        pool_add_k<<<(int)((tot + 255) / 256), 256, 0, stream>>>(buf1, batch, pooled);
    }
    fc_head_k<<<N_GRAPHS, 64, 0, stream>>>(pooled, w_fc1, b_fc1, w_fc2, b_fc2, out);
}

// Round 3
// 848.353 us; speedup vs baseline: 2.5402x; 2.5402x over previous
//
#include <hip/hip_runtime.h>

#define N_NODES 200000
#define N_EDGES 600000
#define N_GRAPHS 10000
#define F_NODE 32
#define HDIM 128
#define BN_EPS 1e-5f

typedef unsigned short ushort_t;
typedef unsigned int uint_t;
typedef __attribute__((ext_vector_type(8))) short short8;
typedef __attribute__((ext_vector_type(4))) float f32x4;

__device__ __forceinline__ ushort_t f2bf(float f) {
    uint_t u = __builtin_bit_cast(uint_t, f);
    u += 0x7FFFu + ((u >> 16) & 1u);   // RNE
    return (ushort_t)(u >> 16);
}
__device__ __forceinline__ float bf2f(ushort_t h) {
    uint_t u = ((uint_t)h) << 16;
    return __builtin_bit_cast(float, u);
}

// ---------------- zero fill (graph-capture-safe memset) ----------------
__global__ __launch_bounds__(256) void fill_zero_k(float* __restrict__ p, long long n)
{
    long long gid = (long long)blockIdx.x * blockDim.x + threadIdx.x;
    long long stride = (long long)gridDim.x * blockDim.x;
    for (long long i = gid; i < n; i += stride) p[i] = 0.f;
}

// ---------------- weight pre-permute into MFMA B-fragment order ----------------
// Wp[ntg][ks][lane][j] = bf16(W[ks*32 + (lane>>4)*8 + j][ntg*16 + (lane&15)])
template<int K>
__global__ __launch_bounds__(256) void permute_w_k(
    const float* __restrict__ w, ushort_t* __restrict__ wp)
{
    constexpr int KS = K / 32;
    int gid = blockIdx.x * 256 + threadIdx.x;
    if (gid >= K * HDIM) return;
    int idx = gid;
    int j = idx & 7; idx >>= 3;
    int lane = idx & 63; idx >>= 6;
    int ks = idx % KS;
    int ntg = idx / KS;
    int k = ks * 32 + ((lane >> 4) << 3) + j;
    int n = ntg * 16 + (lane & 15);
    wp[gid] = f2bf(w[k * HDIM + n]);
}

// ---------------- scatter-add f32 (layer 1, D=32) ----------------
template<int D>
__global__ __launch_bounds__(256) void scatter_add_f32_k(
    const float* __restrict__ h, const int* __restrict__ src,
    const int* __restrict__ dst, float* __restrict__ agg)
{
    long long gid = (long long)blockIdx.x * blockDim.x + threadIdx.x;
    long long total = (long long)N_EDGES * D;
    if (gid >= total) return;
    int e = (int)(gid / D);
    int f = (int)(gid % D);
    int s = src[e], d = dst[e];
    atomicAdd(&agg[(long long)d * D + f], h[(long long)s * D + f]);
}

// ---------------- scatter-add bf16 source (layers 2,3, D=128) ----------------
__global__ __launch_bounds__(256) void scatter_add_bf16_k(
    const ushort_t* __restrict__ h, const int* __restrict__ src,
    const int* __restrict__ dst, float* __restrict__ agg)
{
    long long gid = (long long)blockIdx.x * blockDim.x + threadIdx.x;
    long long total = (long long)N_EDGES * HDIM;
    if (gid >= total) return;
    int e = (int)(gid >> 7);
    int f = (int)(gid & 127);
    int s = src[e], d = dst[e];
    atomicAdd(&agg[(long long)d * HDIM + f], bf2f(h[(long long)s * HDIM + f]));
}

// ---------------- MFMA GEMM: out = epi( A @ W ) , A = x (+ agg), W pre-permuted ----
// A: [N_NODES, K]  (f32 or bf16; if BN, agg f32 added)
// out: [N_NODES, 128] bf16.  Safe for out == xin (rows staged before write).
// BN epilogue: relu(acc*scale + shift); else relu(acc + bias).
template<int K, bool IN_BF16, bool BN>
__global__ __launch_bounds__(256) void gemm_mfma_k(
    const void* __restrict__ xin, const float* __restrict__ agg,
    const ushort_t* __restrict__ wp,
    const float* __restrict__ b1, const float* __restrict__ gamma,
    const float* __restrict__ beta, const float* __restrict__ rmean,
    const float* __restrict__ rvar,
    ushort_t* __restrict__ out)
{
    constexpr int KS = K / 32;
    constexpr int LDA = K + 8;           // ushort units; +8 pad -> 2-way bank alias (free)
    __shared__ ushort_t A_lds[64 * LDA];

    const int tid  = threadIdx.x;
    const int lane = tid & 63;
    const int wid  = tid >> 6;           // wave 0..3
    const int wm   = wid >> 1;           // wave M index (0..1) -> 32 rows
    const int wn   = wid & 1;            // wave N index (0..1) -> 64 cols
    const long long m0 = (long long)blockIdx.x * 64;

    // ---- B fragments: M-invariant, load once from pre-permuted global ----
    short8 bfrag[4][KS];
    #pragma unroll
    for (int nt = 0; nt < 4; ++nt) {
        #pragma unroll
        for (int ks = 0; ks < KS; ++ks) {
            int ntg = wn * 4 + nt;
            bfrag[nt][ks] = *reinterpret_cast<const short8*>(
                wp + ((((ntg * KS) + ks) * 64 + lane) << 3));
        }
    }

    // ---- stage A tile (64 x K) to LDS as bf16 ----
    for (int i = tid; i < 64 * K / 4; i += 256) {
        int row = i / (K / 4);
        int c4  = i % (K / 4);
        long long g = (m0 + row) * K + (long long)c4 * 4;
        uint2 packed;
        if (!IN_BF16) {
            const float* xp = (const float*)xin;
            float4 xv = *reinterpret_cast<const float4*>(xp + g);
            float4 av = *reinterpret_cast<const float4*>(agg + g);
            packed.x = (uint_t)f2bf(xv.x + av.x) | ((uint_t)f2bf(xv.y + av.y) << 16);
            packed.y = (uint_t)f2bf(xv.z + av.z) | ((uint_t)f2bf(xv.w + av.w) << 16);
        } else if (BN) {
            const ushort_t* xp = (const ushort_t*)xin;
            uint2 hv = *reinterpret_cast<const uint2*>(xp + g);
            float4 av = *reinterpret_cast<const float4*>(agg + g);
            packed.x = (uint_t)f2bf(bf2f(hv.x & 0xffff) + av.x) |
                       ((uint_t)f2bf(bf2f(hv.x >> 16) + av.y) << 16);
            packed.y = (uint_t)f2bf(bf2f(hv.y & 0xffff) + av.z) |
                       ((uint_t)f2bf(bf2f(hv.y >> 16) + av.w) << 16);
        } else {
            const ushort_t* xp = (const ushort_t*)xin;
            packed = *reinterpret_cast<const uint2*>(xp + g);
        }
        *reinterpret_cast<uint2*>(&A_lds[row * LDA + c4 * 4]) = packed;
    }
    __syncthreads();

    // ---- K loop ----
    f32x4 acc[2][4] = {};
    #pragma unroll
    for (int ks = 0; ks < KS; ++ks) {
        short8 afrag[2];
        #pragma unroll
        for (int mt = 0; mt < 2; ++mt) {
            int row = wm * 32 + mt * 16 + (lane & 15);
            int col = ks * 32 + ((lane >> 4) << 3);
            afrag[mt] = *reinterpret_cast<const short8*>(&A_lds[row * LDA + col]);
        }
        #pragma unroll
        for (int mt = 0; mt < 2; ++mt) {
            #pragma unroll
            for (int nt = 0; nt < 4; ++nt) {
                acc[mt][nt] = __builtin_amdgcn_mfma_f32_16x16x32_bf16(
                    afrag[mt], bfrag[nt][ks], acc[mt][nt], 0, 0, 0);
            }
        }
    }

    // ---- epilogue: BN/bias + ReLU, store bf16 ----
    #pragma unroll
    for (int nt = 0; nt < 4; ++nt) {
        int col = wn * 64 + nt * 16 + (lane & 15);
        float scale, shift;
        if (BN) {
            float rs = rsqrtf(rvar[col] + BN_EPS);
            scale = gamma[col] * rs;
            shift = (b1[col] - rmean[col]) * scale + beta[col];
        } else {
            scale = 1.f;
            shift = b1[col];   // bias
        }
        #pragma unroll
        for (int mt = 0; mt < 2; ++mt) {
            long long rowb = m0 + wm * 32 + mt * 16 + ((lane >> 4) << 2);
            #pragma unroll
            for (int r = 0; r < 4; ++r) {
                float v = fmaxf(acc[mt][nt][r] * scale + shift, 0.f);
                out[(rowb + r) * HDIM + col] = f2bf(v);
            }
        }
    }
}

// ---------------- pool: pooled[batch[n]] += h[n] (bf16 h, strip reduce) ----
__global__ __launch_bounds__(256) void pool_add_bf16_k(
    const ushort_t* __restrict__ h, const int* __restrict__ batch,
    float* __restrict__ pooled)
{
    const int nStrips = (N_NODES + 7) / 8;
    long long gid = (long long)blockIdx.x * blockDim.x + threadIdx.x;
    long long total = (long long)nStrips * HDIM;
    if (gid >= total) return;
    int strip = (int)(gid >> 7);
    int j = (int)(gid & 127);
    int n0 = strip * 8;
    int nend = n0 + 8; if (nend > N_NODES) nend = N_NODES;
    int curb = batch[n0];
    float sum = 0.f;
    for (int n = n0; n < nend; ++n) {
        int b = batch[n];
        if (b != curb) {
            atomicAdd(&pooled[(long long)curb * HDIM + j], sum);
            curb = b; sum = 0.f;
        }
        sum += bf2f(h[(long long)n * HDIM + j]);
    }
    atomicAdd(&pooled[(long long)curb * HDIM + j], sum);
}

// ---------------- head ----------------
__global__ __launch_bounds__(64) void fc_head_k(
    const float* __restrict__ pooled,
    const float* __restrict__ w_fc1, const float* __restrict__ b_fc1,
    const float* __restrict__ w_fc2, const float* __restrict__ b_fc2,
    float* __restrict__ out)
{
    int g = blockIdx.x;
    int j = threadIdx.x;   // 0..63
    __shared__ float p[HDIM];
    p[j]      = pooled[(long long)g * HDIM + j];
    p[j + 64] = pooled[(long long)g * HDIM + j + 64];
    __syncthreads();

    float acc = b_fc1[j];
    #pragma unroll 8
    for (int k = 0; k < HDIM; ++k) acc += p[k] * w_fc1[k * 64 + j];
    acc = fmaxf(acc, 0.f);

    float v = acc * w_fc2[j];
    #pragma unroll
    for (int off = 32; off > 0; off >>= 1) v += __shfl_down(v, off, 64);
    if (j == 0) out[g] = v + b_fc2[0];
}

extern "C" void kernel_launch(void* const* d_in, const int* in_sizes, int n_in,
                              void* d_out, int out_size, void* d_ws, size_t ws_size,
                              hipStream_t stream) {
    const float* x     = (const float*)d_in[0];
    const int*   ei    = (const int*)d_in[1];
    const int*   src   = ei;                // edge_index[0]
    const int*   dst   = ei + N_EDGES;      // edge_index[1]
    const int*   batch = (const int*)d_in[3];
    const float* L[3][8];
    for (int l = 0; l < 3; ++l)
        for (int p = 0; p < 8; ++p)
            L[l][p] = (const float*)d_in[4 + 8 * l + p];
    const float* w_fc1 = (const float*)d_in[30];
    const float* b_fc1 = (const float*)d_in[31];
    const float* w_fc2 = (const float*)d_in[32];
    const float* b_fc2 = (const float*)d_in[33];
    float* out = (float*)d_out;

    // ---- workspace layout (total 209.92 MB, same as proven footprint) ----
    // agg   f32  [N,128]  @ 0
    // hA    bf16 [N,128]  @ 102,400,000
    // hB    bf16 [N,128]  @ 153,600,000
    // pooled f32 [G,128]  @ 204,800,000   (Wp aliases this region until pool)
    const size_t NH = (size_t)N_NODES * HDIM;
    char* base = (char*)d_ws;
    float*    agg    = (float*)base;
    ushort_t* hA     = (ushort_t*)(base + NH * 4);
    ushort_t* hB     = (ushort_t*)(base + NH * 4 + NH * 2);
    float*    pooled = (float*)(base + NH * 4 + NH * 4);
    ushort_t* wpBase = (ushort_t*)pooled;   // weights live here until pool phase

    ushort_t* wp1_1 = wpBase;                 // 32*128
    ushort_t* wp2_1 = wp1_1 + 32 * HDIM;      // 128*128 each below
    ushort_t* wp1_2 = wp2_1 + HDIM * HDIM;
    ushort_t* wp2_2 = wp1_2 + HDIM * HDIM;
    ushort_t* wp1_3 = wp2_2 + HDIM * HDIM;
    ushort_t* wp2_3 = wp1_3 + HDIM * HDIM;

    const int GEMM_GRID = (N_NODES + 63) / 64;   // 3125
    const int FILL_GRID = 2048;

    // ---- pre-permute weights into MFMA fragment order ----
    permute_w_k<F_NODE><<<(F_NODE * HDIM + 255) / 256, 256, 0, stream>>>(L[0][0], wp1_1);
    permute_w_k<HDIM><<<(HDIM * HDIM + 255) / 256, 256, 0, stream>>>(L[0][6], wp2_1);
    permute_w_k<HDIM><<<(HDIM * HDIM + 255) / 256, 256, 0, stream>>>(L[1][0], wp1_2);
    permute_w_k<HDIM><<<(HDIM * HDIM + 255) / 256, 256, 0, stream>>>(L[1][6], wp2_2);
    permute_w_k<HDIM><<<(HDIM * HDIM + 255) / 256, 256, 0, stream>>>(L[2][0], wp1_3);
    permute_w_k<HDIM><<<(HDIM * HDIM + 255) / 256, 256, 0, stream>>>(L[2][6], wp2_3);

    // ---------- layer 1 (K=32): scatter x -> agg32; gemm1 -> hA; gemm2 in-place ----
    fill_zero_k<<<FILL_GRID, 256, 0, stream>>>(agg, (long long)N_NODES * F_NODE);
    {
        long long tot = (long long)N_EDGES * F_NODE;
        scatter_add_f32_k<F_NODE><<<(int)((tot + 255) / 256), 256, 0, stream>>>(x, src, dst, agg);
    }
    gemm_mfma_k<F_NODE, false, true><<<GEMM_GRID, 256, 0, stream>>>(
        x, agg, wp1_1, L[0][1], L[0][2], L[0][3], L[0][4], L[0][5], hA);
    gemm_mfma_k<HDIM, true, false><<<GEMM_GRID, 256, 0, stream>>>(
        hA, nullptr, wp2_1, L[0][7], nullptr, nullptr, nullptr, nullptr, hA);

    // ---------- layer 2: h = hA; scatter -> agg; gemm1 -> hB; gemm2 in-place ----
    fill_zero_k<<<FILL_GRID, 256, 0, stream>>>(agg, (long long)NH);
    {
        long long tot = (long long)N_EDGES * HDIM;
        scatter_add_bf16_k<<<(int)((tot + 255) / 256), 256, 0, stream>>>(hA, src, dst, agg);
    }
    gemm_mfma_k<HDIM, true, true><<<GEMM_GRID, 256, 0, stream>>>(
        hA, agg, wp1_2, L[1][1], L[1][2], L[1][3], L[1][4], L[1][5], hB);
    gemm_mfma_k<HDIM, true, false><<<GEMM_GRID, 256, 0, stream>>>(
        hB, nullptr, wp2_2, L[1][7], nullptr, nullptr, nullptr, nullptr, hB);

    // ---------- layer 3: h = hB; scatter -> agg; gemm1 -> hA; gemm2 in-place ----
    fill_zero_k<<<FILL_GRID, 256, 0, stream>>>(agg, (long long)NH);
    {
        long long tot = (long long)N_EDGES * HDIM;
        scatter_add_bf16_k<<<(int)((tot + 255) / 256), 256, 0, stream>>>(hB, src, dst, agg);
    }
    gemm_mfma_k<HDIM, true, true><<<GEMM_GRID, 256, 0, stream>>>(
        hB, agg, wp1_3, L[2][1], L[2][2], L[2][3], L[2][4], L[2][5], hA);
    gemm_mfma_k<HDIM, true, false><<<GEMM_GRID, 256, 0, stream>>>(
        hA, nullptr, wp2_3, L[2][7], nullptr, nullptr, nullptr, nullptr, hA);

    // ---------- pool + head (pooled region now free of Wp uses) ----------
    fill_zero_k<<<FILL_GRID, 256, 0, stream>>>(pooled, (long long)N_GRAPHS * HDIM);
    {
        const int nStrips = (N_NODES + 7) / 8;
        long long tot = (long long)nStrips * HDIM;
        pool_add_bf16_k<<<(int)((tot + 255) / 256), 256, 0, stream>>>(hA, batch, pooled);
    }
    fc_head_k<<<N_GRAPHS, 64, 0, stream>>>(pooled, w_fc1, b_fc1, w_fc2, b_fc2, out);
}

// Round 4
// 337.628 us; speedup vs baseline: 6.3827x; 2.5127x over previous
//
#include <hip/hip_runtime.h>

#define N_NODES 200000
#define N_EDGES 600000
#define N_GRAPHS 10000
#define F_NODE 32
#define HDIM 128
#define BN_EPS 1e-5f

typedef unsigned short ushort_t;
typedef unsigned int uint_t;
typedef __attribute__((ext_vector_type(8))) short short8;
typedef __attribute__((ext_vector_type(4))) float f32x4;

__device__ __forceinline__ ushort_t f2bf(float f) {
    uint_t u = __builtin_bit_cast(uint_t, f);
    u += 0x7FFFu + ((u >> 16) & 1u);   // RNE
    return (ushort_t)(u >> 16);
}
__device__ __forceinline__ float bf2f(ushort_t h) {
    uint_t u = ((uint_t)h) << 16;
    return __builtin_bit_cast(float, u);
}

// ---------------- zero fill (works for f32/int zeros) ----------------
__global__ __launch_bounds__(256) void fill_zero_k(uint_t* __restrict__ p, long long n)
{
    long long gid = (long long)blockIdx.x * blockDim.x + threadIdx.x;
    long long stride = (long long)gridDim.x * blockDim.x;
    for (long long i = gid; i < n; i += stride) p[i] = 0u;
}

// ---------------- CSR build ----------------
__global__ __launch_bounds__(256) void hist_k(const int* __restrict__ dst, int* __restrict__ deg)
{
    int e = blockIdx.x * 256 + threadIdx.x;
    if (e < N_EDGES) atomicAdd(&deg[dst[e]], 1);
}

__global__ __launch_bounds__(256) void scan_blocks_k(
    const int* __restrict__ deg, int* __restrict__ incl, int* __restrict__ bsum)
{
    __shared__ int sh[256];
    int i = blockIdx.x * 256 + threadIdx.x;
    int v = (i < N_NODES) ? deg[i] : 0;
    sh[threadIdx.x] = v;
    __syncthreads();
    #pragma unroll
    for (int off = 1; off < 256; off <<= 1) {
        int t = (threadIdx.x >= off) ? sh[threadIdx.x - off] : 0;
        __syncthreads();
        sh[threadIdx.x] += t;
        __syncthreads();
    }
    if (i < N_NODES) incl[i] = sh[threadIdx.x];
    if (threadIdx.x == 255) bsum[blockIdx.x] = sh[255];
}

__global__ __launch_bounds__(256) void scan_bsum_k(int* __restrict__ bsum, int nb)
{
    __shared__ int sh[256];
    int run = 0;
    for (int base = 0; base < nb; base += 256) {
        int i = base + threadIdx.x;
        int v = (i < nb) ? bsum[i] : 0;
        sh[threadIdx.x] = v;
        __syncthreads();
        #pragma unroll
        for (int off = 1; off < 256; off <<= 1) {
            int t = (threadIdx.x >= off) ? sh[threadIdx.x - off] : 0;
            __syncthreads();
            sh[threadIdx.x] += t;
            __syncthreads();
        }
        if (i < nb) bsum[i] = run + sh[threadIdx.x] - v;  // exclusive
        run += sh[255];
        __syncthreads();
    }
}

__global__ __launch_bounds__(256) void finalize_csr_k(
    const int* __restrict__ deg, const int* __restrict__ incl,
    const int* __restrict__ bsum, int* __restrict__ rowptr, int* __restrict__ cursor)
{
    int i = blockIdx.x * 256 + threadIdx.x;
    if (i >= N_NODES) return;
    int v = incl[i] + bsum[blockIdx.x];
    rowptr[i + 1] = v;
    cursor[i] = v - deg[i];
    if (i == 0) rowptr[0] = 0;
}

__global__ __launch_bounds__(256) void fill_edges_k(
    const int* __restrict__ src, const int* __restrict__ dst,
    int* __restrict__ cursor, int* __restrict__ col)
{
    int e = blockIdx.x * 256 + threadIdx.x;
    if (e >= N_EDGES) return;
    int pos = atomicAdd(&cursor[dst[e]], 1);
    col[pos] = src[e];
}

// ---------------- weight pre-permute into MFMA B-fragment order ----------------
template<int K>
__global__ __launch_bounds__(256) void permute_w_k(
    const float* __restrict__ w, ushort_t* __restrict__ wp)
{
    constexpr int KS = K / 32;
    int gid = blockIdx.x * 256 + threadIdx.x;
    if (gid >= K * HDIM) return;
    int idx = gid;
    int j = idx & 7; idx >>= 3;
    int lane = idx & 63; idx >>= 6;
    int ks = idx % KS;
    int ntg = idx / KS;
    int k = ks * 32 + ((lane >> 4) << 3) + j;
    int n = ntg * 16 + (lane & 15);
    wp[gid] = f2bf(w[k * HDIM + n]);
}

// ---------------- fused gather + GEMM1: out = relu(BN((x[n]+Σnbr x) @ W + b1)) ----
// xin: [N,K] f32 (!IN_BF16) or bf16; out: [N,128] bf16 (must differ from xin).
template<int K, bool IN_BF16>
__global__ __launch_bounds__(256) void gemm1_gather_k(
    const void* __restrict__ xin, const int* __restrict__ rowptr,
    const int* __restrict__ col, const ushort_t* __restrict__ wp,
    const float* __restrict__ b1, const float* __restrict__ gamma,
    const float* __restrict__ beta, const float* __restrict__ rmean,
    const float* __restrict__ rvar, ushort_t* __restrict__ out)
{
    constexpr int KS  = K / 32;
    constexpr int LDA = K + 8;
    constexpr int FPT = K / 4;
    __shared__ ushort_t A_lds[64 * LDA];

    const int tid  = threadIdx.x;
    const int lane = tid & 63;
    const int wid  = tid >> 6;
    const int wm   = wid >> 1;
    const int wn   = wid & 1;
    const long long m0 = (long long)blockIdx.x * 64;

    // ---- gather-stage: 4 threads per row, FPT features each, f32 accumulate ----
    {
        int row = tid >> 2;
        int fq  = (tid & 3) * FPT;
        long long n = m0 + row;
        float acc[FPT];
        if (!IN_BF16) {
            const float* xp = (const float*)xin + n * K + fq;
            #pragma unroll
            for (int v = 0; v < FPT / 4; ++v) {
                float4 f = *reinterpret_cast<const float4*>(xp + v * 4);
                acc[v*4+0] = f.x; acc[v*4+1] = f.y; acc[v*4+2] = f.z; acc[v*4+3] = f.w;
            }
        } else {
            const uint4* xp = (const uint4*)((const ushort_t*)xin + n * (long long)K + fq);
            #pragma unroll
            for (int v = 0; v < FPT / 8; ++v) {
                uint4 u = xp[v];
                acc[v*8+0]=bf2f(u.x&0xffff); acc[v*8+1]=bf2f(u.x>>16);
                acc[v*8+2]=bf2f(u.y&0xffff); acc[v*8+3]=bf2f(u.y>>16);
                acc[v*8+4]=bf2f(u.z&0xffff); acc[v*8+5]=bf2f(u.z>>16);
                acc[v*8+6]=bf2f(u.w&0xffff); acc[v*8+7]=bf2f(u.w>>16);
            }
        }
        int p0 = rowptr[n], p1 = rowptr[n + 1];
        for (int p = p0; p < p1; ++p) {
            long long s = col[p];
            if (!IN_BF16) {
                const float* sp = (const float*)xin + s * K + fq;
                #pragma unroll
                for (int v = 0; v < FPT / 4; ++v) {
                    float4 f = *reinterpret_cast<const float4*>(sp + v * 4);
                    acc[v*4+0]+=f.x; acc[v*4+1]+=f.y; acc[v*4+2]+=f.z; acc[v*4+3]+=f.w;
                }
            } else {
                const uint4* sp = (const uint4*)((const ushort_t*)xin + s * (long long)K + fq);
                #pragma unroll
                for (int v = 0; v < FPT / 8; ++v) {
                    uint4 u = sp[v];
                    acc[v*8+0]+=bf2f(u.x&0xffff); acc[v*8+1]+=bf2f(u.x>>16);
                    acc[v*8+2]+=bf2f(u.y&0xffff); acc[v*8+3]+=bf2f(u.y>>16);
                    acc[v*8+4]+=bf2f(u.z&0xffff); acc[v*8+5]+=bf2f(u.z>>16);
                    acc[v*8+6]+=bf2f(u.w&0xffff); acc[v*8+7]+=bf2f(u.w>>16);
                }
            }
        }
        #pragma unroll
        for (int f = 0; f < FPT; f += 2) {
            uint_t pk = (uint_t)f2bf(acc[f]) | ((uint_t)f2bf(acc[f+1]) << 16);
            *reinterpret_cast<uint_t*>(&A_lds[row * LDA + fq + f]) = pk;
        }
    }
    __syncthreads();

    // ---- B fragments (loaded after staging to keep live ranges disjoint) ----
    short8 bfrag[4][KS];
    #pragma unroll
    for (int nt = 0; nt < 4; ++nt) {
        #pragma unroll
        for (int ks = 0; ks < KS; ++ks) {
            int ntg = wn * 4 + nt;
            bfrag[nt][ks] = *reinterpret_cast<const short8*>(
                wp + ((((ntg * KS) + ks) * 64 + lane) << 3));
        }
    }

    // ---- K loop ----
    f32x4 acc[2][4] = {};
    #pragma unroll
    for (int ks = 0; ks < KS; ++ks) {
        short8 afrag[2];
        #pragma unroll
        for (int mt = 0; mt < 2; ++mt) {
            int row = wm * 32 + mt * 16 + (lane & 15);
            int c   = ks * 32 + ((lane >> 4) << 3);
            afrag[mt] = *reinterpret_cast<const short8*>(&A_lds[row * LDA + c]);
        }
        #pragma unroll
        for (int mt = 0; mt < 2; ++mt) {
            #pragma unroll
            for (int nt = 0; nt < 4; ++nt) {
                acc[mt][nt] = __builtin_amdgcn_mfma_f32_16x16x32_bf16(
                    afrag[mt], bfrag[nt][ks], acc[mt][nt], 0, 0, 0);
            }
        }
    }

    // ---- epilogue: BN + ReLU, store bf16 ----
    #pragma unroll
    for (int nt = 0; nt < 4; ++nt) {
        int c = wn * 64 + nt * 16 + (lane & 15);
        float rs = rsqrtf(rvar[c] + BN_EPS);
        float scale = gamma[c] * rs;
        float shift = (b1[c] - rmean[c]) * scale + beta[c];
        #pragma unroll
        for (int mt = 0; mt < 2; ++mt) {
            long long rowb = m0 + wm * 32 + mt * 16 + ((lane >> 4) << 2);
            #pragma unroll
            for (int r = 0; r < 4; ++r) {
                float v = fmaxf(acc[mt][nt][r] * scale + shift, 0.f);
                out[(rowb + r) * HDIM + c] = f2bf(v);
            }
        }
    }
}

// ---------------- GEMM2: out = relu(t @ W2 + b2), bf16 in/out, in-place safe ----
__global__ __launch_bounds__(256) void gemm2_mfma_k(
    const ushort_t* __restrict__ xin, const ushort_t* __restrict__ wp,
    const float* __restrict__ b2, ushort_t* __restrict__ out)
{
    constexpr int K = HDIM, KS = K / 32, LDA = K + 8;
    __shared__ ushort_t A_lds[64 * LDA];

    const int tid  = threadIdx.x;
    const int lane = tid & 63;
    const int wid  = tid >> 6;
    const int wm   = wid >> 1;
    const int wn   = wid & 1;
    const long long m0 = (long long)blockIdx.x * 64;

    for (int i = tid; i < 64 * K / 4; i += 256) {
        int row = i / (K / 4);
        int c4  = i % (K / 4);
        long long g = (m0 + row) * K + (long long)c4 * 4;
        uint2 packed = *reinterpret_cast<const uint2*>(xin + g);
        *reinterpret_cast<uint2*>(&A_lds[row * LDA + c4 * 4]) = packed;
    }
    __syncthreads();

    short8 bfrag[4][KS];
    #pragma unroll
    for (int nt = 0; nt < 4; ++nt) {
        #pragma unroll
        for (int ks = 0; ks < KS; ++ks) {
            int ntg = wn * 4 + nt;
            bfrag[nt][ks] = *reinterpret_cast<const short8*>(
                wp + ((((ntg * KS) + ks) * 64 + lane) << 3));
        }
    }

    f32x4 acc[2][4] = {};
    #pragma unroll
    for (int ks = 0; ks < KS; ++ks) {
        short8 afrag[2];
        #pragma unroll
        for (int mt = 0; mt < 2; ++mt) {
            int row = wm * 32 + mt * 16 + (lane & 15);
            int c   = ks * 32 + ((lane >> 4) << 3);
            afrag[mt] = *reinterpret_cast<const short8*>(&A_lds[row * LDA + c]);
        }
        #pragma unroll
        for (int mt = 0; mt < 2; ++mt) {
            #pragma unroll
            for (int nt = 0; nt < 4; ++nt) {
                acc[mt][nt] = __builtin_amdgcn_mfma_f32_16x16x32_bf16(
                    afrag[mt], bfrag[nt][ks], acc[mt][nt], 0, 0, 0);
            }
        }
    }

    #pragma unroll
    for (int nt = 0; nt < 4; ++nt) {
        int c = wn * 64 + nt * 16 + (lane & 15);
        float bias = b2[c];
        #pragma unroll
        for (int mt = 0; mt < 2; ++mt) {
            long long rowb = m0 + wm * 32 + mt * 16 + ((lane >> 4) << 2);
            #pragma unroll
            for (int r = 0; r < 4; ++r) {
                float v = fmaxf(acc[mt][nt][r] + bias, 0.f);
                out[(rowb + r) * HDIM + c] = f2bf(v);
            }
        }
    }
}

// ---------------- pool: pooled[batch[n]] += h[n] (bf16 h, strip reduce) ----
__global__ __launch_bounds__(256) void pool_add_bf16_k(
    const ushort_t* __restrict__ h, const int* __restrict__ batch,
    float* __restrict__ pooled)
{
    const int nStrips = (N_NODES + 7) / 8;
    long long gid = (long long)blockIdx.x * blockDim.x + threadIdx.x;
    long long total = (long long)nStrips * HDIM;
    if (gid >= total) return;
    int strip = (int)(gid >> 7);
    int j = (int)(gid & 127);
    int n0 = strip * 8;
    int nend = n0 + 8; if (nend > N_NODES) nend = N_NODES;
    int curb = batch[n0];
    float sum = 0.f;
    for (int n = n0; n < nend; ++n) {
        int b = batch[n];
        if (b != curb) {
            atomicAdd(&pooled[(long long)curb * HDIM + j], sum);
            curb = b; sum = 0.f;
        }
        sum += bf2f(h[(long long)n * HDIM + j]);
    }
    atomicAdd(&pooled[(long long)curb * HDIM + j], sum);
}

// ---------------- head ----------------
__global__ __launch_bounds__(64) void fc_head_k(
    const float* __restrict__ pooled,
    const float* __restrict__ w_fc1, const float* __restrict__ b_fc1,
    const float* __restrict__ w_fc2, const float* __restrict__ b_fc2,
    float* __restrict__ out)
{
    int g = blockIdx.x;
    int j = threadIdx.x;   // 0..63
    __shared__ float p[HDIM];
    p[j]      = pooled[(long long)g * HDIM + j];
    p[j + 64] = pooled[(long long)g * HDIM + j + 64];
    __syncthreads();

    float acc = b_fc1[j];
    #pragma unroll 8
    for (int k = 0; k < HDIM; ++k) acc += p[k] * w_fc1[k * 64 + j];
    acc = fmaxf(acc, 0.f);

    float v = acc * w_fc2[j];
    #pragma unroll
    for (int off = 32; off > 0; off >>= 1) v += __shfl_down(v, off, 64);
    if (j == 0) out[g] = v + b_fc2[0];
}

extern "C" void kernel_launch(void* const* d_in, const int* in_sizes, int n_in,
                              void* d_out, int out_size, void* d_ws, size_t ws_size,
                              hipStream_t stream) {
    const float* x     = (const float*)d_in[0];
    const int*   ei    = (const int*)d_in[1];
    const int*   src   = ei;                // edge_index[0]
    const int*   dst   = ei + N_EDGES;      // edge_index[1]
    const int*   batch = (const int*)d_in[3];
    const float* L[3][8];
    for (int l = 0; l < 3; ++l)
        for (int p = 0; p < 8; ++p)
            L[l][p] = (const float*)d_in[4 + 8 * l + p];
    const float* w_fc1 = (const float*)d_in[30];
    const float* b_fc1 = (const float*)d_in[31];
    const float* w_fc2 = (const float*)d_in[32];
    const float* b_fc2 = (const float*)d_in[33];
    float* out = (float*)d_out;

    // ---- workspace layout (bytes), total ~113.6 MB (< proven 210 MB) ----
    char* base = (char*)d_ws;
    ushort_t* hA     = (ushort_t*)(base);                 // bf16 [N,128] 51.2 MB
    ushort_t* hB     = (ushort_t*)(base + 51200000);      // bf16 [N,128] 51.2 MB
    float*    pooled = (float*)   (base + 102400000);     // f32 [G,128] 5.12 MB
    ushort_t* wpBase = (ushort_t*)(base + 107520000);     // 172 KB
    int*      deg    = (int*)     (base + 108000000);     // 800 KB
    int*      incl   = (int*)     (base + 108800000);     // 800 KB
    int*      bsum   = (int*)     (base + 109600000);     // 4 KB
    int*      rowptr = (int*)     (base + 109604096);     // 800,004 B
    int*      cursor = (int*)     (base + 110404100);     // 800 KB
    int*      colarr = (int*)     (base + 111204100);     // 2.4 MB

    ushort_t* wp1_1 = wpBase;                 // 32*128
    ushort_t* wp2_1 = wp1_1 + 32 * HDIM;
    ushort_t* wp1_2 = wp2_1 + HDIM * HDIM;
    ushort_t* wp2_2 = wp1_2 + HDIM * HDIM;
    ushort_t* wp1_3 = wp2_2 + HDIM * HDIM;
    ushort_t* wp2_3 = wp1_3 + HDIM * HDIM;

    const int GEMM_GRID = N_NODES / 64;          // 3125 (divides exactly)
    const int NB_NODE   = (N_NODES + 255) / 256; // 782
    const int NB_EDGE   = (N_EDGES + 255) / 256; // 2344

    // ---- weight permutes ----
    permute_w_k<F_NODE><<<(F_NODE * HDIM + 255) / 256, 256, 0, stream>>>(L[0][0], wp1_1);
    permute_w_k<HDIM><<<(HDIM * HDIM + 255) / 256, 256, 0, stream>>>(L[0][6], wp2_1);
    permute_w_k<HDIM><<<(HDIM * HDIM + 255) / 256, 256, 0, stream>>>(L[1][0], wp1_2);
    permute_w_k<HDIM><<<(HDIM * HDIM + 255) / 256, 256, 0, stream>>>(L[1][6], wp2_2);
    permute_w_k<HDIM><<<(HDIM * HDIM + 255) / 256, 256, 0, stream>>>(L[2][0], wp1_3);
    permute_w_k<HDIM><<<(HDIM * HDIM + 255) / 256, 256, 0, stream>>>(L[2][6], wp2_3);

    // ---- CSR build (every call; deterministic up to f32 rounding in gather) ----
    fill_zero_k<<<512, 256, 0, stream>>>((uint_t*)deg, N_NODES);
    hist_k<<<NB_EDGE, 256, 0, stream>>>(dst, deg);
    scan_blocks_k<<<NB_NODE, 256, 0, stream>>>(deg, incl, bsum);
    scan_bsum_k<<<1, 256, 0, stream>>>(bsum, NB_NODE);
    finalize_csr_k<<<NB_NODE, 256, 0, stream>>>(deg, incl, bsum, rowptr, cursor);
    fill_edges_k<<<NB_EDGE, 256, 0, stream>>>(src, dst, cursor, colarr);

    // ---- layer 1 (K=32, f32 input x) ----
    gemm1_gather_k<F_NODE, false><<<GEMM_GRID, 256, 0, stream>>>(
        x, rowptr, colarr, wp1_1, L[0][1], L[0][2], L[0][3], L[0][4], L[0][5], hA);
    gemm2_mfma_k<<<GEMM_GRID, 256, 0, stream>>>(hA, wp2_1, L[0][7], hA);

    // ---- layer 2 ----
    gemm1_gather_k<HDIM, true><<<GEMM_GRID, 256, 0, stream>>>(
        hA, rowptr, colarr, wp1_2, L[1][1], L[1][2], L[1][3], L[1][4], L[1][5], hB);
    gemm2_mfma_k<<<GEMM_GRID, 256, 0, stream>>>(hB, wp2_2, L[1][7], hB);

    // ---- layer 3 ----
    gemm1_gather_k<HDIM, true><<<GEMM_GRID, 256, 0, stream>>>(
        hB, rowptr, colarr, wp1_3, L[2][1], L[2][2], L[2][3], L[2][4], L[2][5], hA);
    gemm2_mfma_k<<<GEMM_GRID, 256, 0, stream>>>(hA, wp2_3, L[2][7], hA);

    // ---- pool + head ----
    fill_zero_k<<<512, 256, 0, stream>>>((uint_t*)pooled, (long long)N_GRAPHS * HDIM);
    {
        const int nStrips = (N_NODES + 7) / 8;
        long long tot = (long long)nStrips * HDIM;
        pool_add_bf16_k<<<(int)((tot + 255) / 256), 256, 0, stream>>>(hA, batch, pooled);
    }
    fc_head_k<<<N_GRAPHS, 64, 0, stream>>>(pooled, w_fc1, b_fc1, w_fc2, b_fc2, out);
}

// Round 5
// 262.910 us; speedup vs baseline: 8.1967x; 1.2842x over previous
//
#include <hip/hip_runtime.h>

#define N_NODES 200000
#define N_EDGES 600000
#define N_GRAPHS 10000
#define F_NODE 32
#define HDIM 128
#define BN_EPS 1e-5f

typedef unsigned short ushort_t;
typedef unsigned int uint_t;
typedef __attribute__((ext_vector_type(8))) short short8;
typedef __attribute__((ext_vector_type(4))) float f32x4;

__device__ __forceinline__ ushort_t f2bf(float f) {
    uint_t u = __builtin_bit_cast(uint_t, f);
    u += 0x7FFFu + ((u >> 16) & 1u);   // RNE
    return (ushort_t)(u >> 16);
}
__device__ __forceinline__ float bf2f(ushort_t h) {
    uint_t u = ((uint_t)h) << 16;
    return __builtin_bit_cast(float, u);
}

// ---------------- zero fill ----------------
__global__ __launch_bounds__(256) void fill_zero_k(uint_t* __restrict__ p, long long n)
{
    long long gid = (long long)blockIdx.x * blockDim.x + threadIdx.x;
    long long stride = (long long)gridDim.x * blockDim.x;
    for (long long i = gid; i < n; i += stride) p[i] = 0u;
}

// ---------------- f32 -> bf16 convert (x) ----------------
__global__ __launch_bounds__(256) void cvt_bf16_k(
    const float* __restrict__ in, ushort_t* __restrict__ outp, long long n8)
{
    long long gid = (long long)blockIdx.x * blockDim.x + threadIdx.x;
    if (gid >= n8) return;
    const float4* ip = (const float4*)(in + gid * 8);
    float4 a = ip[0], b = ip[1];
    uint4 u;
    u.x = (uint_t)f2bf(a.x) | ((uint_t)f2bf(a.y) << 16);
    u.y = (uint_t)f2bf(a.z) | ((uint_t)f2bf(a.w) << 16);
    u.z = (uint_t)f2bf(b.x) | ((uint_t)f2bf(b.y) << 16);
    u.w = (uint_t)f2bf(b.z) | ((uint_t)f2bf(b.w) << 16);
    *reinterpret_cast<uint4*>(outp + gid * 8) = u;
}

// ---------------- CSR build ----------------
__global__ __launch_bounds__(256) void hist_k(const int* __restrict__ dst, int* __restrict__ deg)
{
    int e = blockIdx.x * 256 + threadIdx.x;
    if (e < N_EDGES) atomicAdd(&deg[dst[e]], 1);
}

__global__ __launch_bounds__(256) void scan_blocks_k(
    const int* __restrict__ deg, int* __restrict__ incl, int* __restrict__ bsum)
{
    __shared__ int sh[256];
    int i = blockIdx.x * 256 + threadIdx.x;
    int v = (i < N_NODES) ? deg[i] : 0;
    sh[threadIdx.x] = v;
    __syncthreads();
    #pragma unroll
    for (int off = 1; off < 256; off <<= 1) {
        int t = (threadIdx.x >= off) ? sh[threadIdx.x - off] : 0;
        __syncthreads();
        sh[threadIdx.x] += t;
        __syncthreads();
    }
    if (i < N_NODES) incl[i] = sh[threadIdx.x];
    if (threadIdx.x == 255) bsum[blockIdx.x] = sh[255];
}

__global__ __launch_bounds__(256) void scan_bsum_k(int* __restrict__ bsum, int nb)
{
    __shared__ int sh[256];
    int run = 0;
    for (int base = 0; base < nb; base += 256) {
        int i = base + threadIdx.x;
        int v = (i < nb) ? bsum[i] : 0;
        sh[threadIdx.x] = v;
        __syncthreads();
        #pragma unroll
        for (int off = 1; off < 256; off <<= 1) {
            int t = (threadIdx.x >= off) ? sh[threadIdx.x - off] : 0;
            __syncthreads();
            sh[threadIdx.x] += t;
            __syncthreads();
        }
        if (i < nb) bsum[i] = run + sh[threadIdx.x] - v;  // exclusive
        run += sh[255];
        __syncthreads();
    }
}

__global__ __launch_bounds__(256) void finalize_csr_k(
    const int* __restrict__ deg, const int* __restrict__ incl,
    const int* __restrict__ bsum, int* __restrict__ rowptr, int* __restrict__ cursor)
{
    int i = blockIdx.x * 256 + threadIdx.x;
    if (i >= N_NODES) return;
    int v = incl[i] + bsum[blockIdx.x];
    rowptr[i + 1] = v;
    cursor[i] = v - deg[i];
    if (i == 0) rowptr[0] = 0;
}

__global__ __launch_bounds__(256) void fill_edges_k(
    const int* __restrict__ src, const int* __restrict__ dst,
    int* __restrict__ cursor, int* __restrict__ col)
{
    int e = blockIdx.x * 256 + threadIdx.x;
    if (e >= N_EDGES) return;
    int pos = atomicAdd(&cursor[dst[e]], 1);
    col[pos] = src[e];
}

// ---------------- weight pre-permute into MFMA B-fragment order ----------------
template<int K>
__global__ __launch_bounds__(256) void permute_w_k(
    const float* __restrict__ w, ushort_t* __restrict__ wp)
{
    constexpr int KS = K / 32;
    int gid = blockIdx.x * 256 + threadIdx.x;
    if (gid >= K * HDIM) return;
    int idx = gid;
    int j = idx & 7; idx >>= 3;
    int lane = idx & 63; idx >>= 6;
    int ks = idx % KS;
    int ntg = idx / KS;
    int k = ks * 32 + ((lane >> 4) << 3) + j;
    int n = ntg * 16 + (lane & 15);
    wp[gid] = f2bf(w[k * HDIM + n]);
}

// ---------------- fused GIN layer: h_out = relu(relu(BN((h+Σnbr h)@W1+b1))@W2+b2) ----
// If POOL: instead of writing h_out, segment-reduce into pooled by batch id.
template<int K, bool POOL>
__global__ __launch_bounds__(256) void fused_layer_k(
    const ushort_t* __restrict__ xin, const int* __restrict__ rowptr,
    const int* __restrict__ col, const ushort_t* __restrict__ wp1,
    const float* __restrict__ b1, const float* __restrict__ gamma,
    const float* __restrict__ beta, const float* __restrict__ rmean,
    const float* __restrict__ rvar, const ushort_t* __restrict__ wp2,
    const float* __restrict__ b2, ushort_t* __restrict__ out,
    const int* __restrict__ batch, float* __restrict__ pooled)
{
    constexpr int KS1   = K / 32;      // K-steps of GEMM1
    constexpr int KS2   = 4;           // GEMM2 is always K=128
    constexpr int LDA   = K + 8;       // stage-in leading dim (ushort)
    constexpr int LDT   = HDIM + 8;    // T leading dim = 136
    constexpr int FPT   = K / 4;       // features per staging thread
    __shared__ ushort_t A_lds[64 * LDT];   // 17408 B; stage-in uses LDA <= LDT
    __shared__ int batch_l[64];

    const int tid  = threadIdx.x;
    const int lane = tid & 63;
    const int wid  = tid >> 6;
    const int wm   = wid >> 1;
    const int wn   = wid & 1;
    const long long m0 = (long long)blockIdx.x * 64;

    if (POOL && tid < 64) batch_l[tid] = batch[m0 + tid];

    // ---- gather-stage: 4 threads per row, FPT features each, f32 accumulate ----
    {
        int row = tid >> 2;
        int fq  = (tid & 3) * FPT;
        long long n = m0 + row;
        float acc[FPT];
        {
            const uint4* xp = (const uint4*)(xin + n * (long long)K + fq);
            #pragma unroll
            for (int v = 0; v < FPT / 8; ++v) {
                uint4 u = xp[v];
                acc[v*8+0]=bf2f(u.x&0xffff); acc[v*8+1]=bf2f(u.x>>16);
                acc[v*8+2]=bf2f(u.y&0xffff); acc[v*8+3]=bf2f(u.y>>16);
                acc[v*8+4]=bf2f(u.z&0xffff); acc[v*8+5]=bf2f(u.z>>16);
                acc[v*8+6]=bf2f(u.w&0xffff); acc[v*8+7]=bf2f(u.w>>16);
            }
        }
        int p0 = rowptr[n], p1 = rowptr[n + 1];
        for (int p = p0; p < p1; ++p) {
            long long s = col[p];
            const uint4* sp = (const uint4*)(xin + s * (long long)K + fq);
            #pragma unroll
            for (int v = 0; v < FPT / 8; ++v) {
                uint4 u = sp[v];
                acc[v*8+0]+=bf2f(u.x&0xffff); acc[v*8+1]+=bf2f(u.x>>16);
                acc[v*8+2]+=bf2f(u.y&0xffff); acc[v*8+3]+=bf2f(u.y>>16);
                acc[v*8+4]+=bf2f(u.z&0xffff); acc[v*8+5]+=bf2f(u.z>>16);
                acc[v*8+6]+=bf2f(u.w&0xffff); acc[v*8+7]+=bf2f(u.w>>16);
            }
        }
        #pragma unroll
        for (int f = 0; f < FPT; f += 2) {
            uint_t pk = (uint_t)f2bf(acc[f]) | ((uint_t)f2bf(acc[f+1]) << 16);
            *reinterpret_cast<uint_t*>(&A_lds[row * LDA + fq + f]) = pk;
        }
    }
    __syncthreads();

    // ---- GEMM1 K-loop ----
    f32x4 acc1[2][4] = {};
    {
        short8 bfrag[4][KS1];
        #pragma unroll
        for (int nt = 0; nt < 4; ++nt)
            #pragma unroll
            for (int ks = 0; ks < KS1; ++ks) {
                int ntg = wn * 4 + nt;
                bfrag[nt][ks] = *reinterpret_cast<const short8*>(
                    wp1 + ((((ntg * KS1) + ks) * 64 + lane) << 3));
            }
        #pragma unroll
        for (int ks = 0; ks < KS1; ++ks) {
            short8 afrag[2];
            #pragma unroll
            for (int mt = 0; mt < 2; ++mt) {
                int row = wm * 32 + mt * 16 + (lane & 15);
                int c   = ks * 32 + ((lane >> 4) << 3);
                afrag[mt] = *reinterpret_cast<const short8*>(&A_lds[row * LDA + c]);
            }
            #pragma unroll
            for (int mt = 0; mt < 2; ++mt)
                #pragma unroll
                for (int nt = 0; nt < 4; ++nt)
                    acc1[mt][nt] = __builtin_amdgcn_mfma_f32_16x16x32_bf16(
                        afrag[mt], bfrag[nt][ks], acc1[mt][nt], 0, 0, 0);
        }
    }
    __syncthreads();   // all waves done reading A_lds

    // ---- BN + ReLU -> T into A_lds (LDT layout) ----
    #pragma unroll
    for (int nt = 0; nt < 4; ++nt) {
        int c = wn * 64 + nt * 16 + (lane & 15);
        float rs = rsqrtf(rvar[c] + BN_EPS);
        float scale = gamma[c] * rs;
        float shift = (b1[c] - rmean[c]) * scale + beta[c];
        #pragma unroll
        for (int mt = 0; mt < 2; ++mt) {
            int rowb = wm * 32 + mt * 16 + ((lane >> 4) << 2);
            #pragma unroll
            for (int r = 0; r < 4; ++r) {
                float v = fmaxf(acc1[mt][nt][r] * scale + shift, 0.f);
                A_lds[(rowb + r) * LDT + c] = f2bf(v);
            }
        }
    }
    __syncthreads();

    // ---- GEMM2 K-loop (K = 128 over T) ----
    f32x4 acc2[2][4] = {};
    {
        short8 bfrag[4][KS2];
        #pragma unroll
        for (int nt = 0; nt < 4; ++nt)
            #pragma unroll
            for (int ks = 0; ks < KS2; ++ks) {
                int ntg = wn * 4 + nt;
                bfrag[nt][ks] = *reinterpret_cast<const short8*>(
                    wp2 + ((((ntg * KS2) + ks) * 64 + lane) << 3));
            }
        #pragma unroll
        for (int ks = 0; ks < KS2; ++ks) {
            short8 afrag[2];
            #pragma unroll
            for (int mt = 0; mt < 2; ++mt) {
                int row = wm * 32 + mt * 16 + (lane & 15);
                int c   = ks * 32 + ((lane >> 4) << 3);
                afrag[mt] = *reinterpret_cast<const short8*>(&A_lds[row * LDT + c]);
            }
            #pragma unroll
            for (int mt = 0; mt < 2; ++mt)
                #pragma unroll
                for (int nt = 0; nt < 4; ++nt)
                    acc2[mt][nt] = __builtin_amdgcn_mfma_f32_16x16x32_bf16(
                        afrag[mt], bfrag[nt][ks], acc2[mt][nt], 0, 0, 0);
        }
    }

    if (!POOL) {
        // ---- epilogue: bias + ReLU, store bf16 to global ----
        #pragma unroll
        for (int nt = 0; nt < 4; ++nt) {
            int c = wn * 64 + nt * 16 + (lane & 15);
            float bias = b2[c];
            #pragma unroll
            for (int mt = 0; mt < 2; ++mt) {
                long long rowb = m0 + wm * 32 + mt * 16 + ((lane >> 4) << 2);
                #pragma unroll
                for (int r = 0; r < 4; ++r) {
                    float v = fmaxf(acc2[mt][nt][r] + bias, 0.f);
                    out[(rowb + r) * HDIM + c] = f2bf(v);
                }
            }
        }
    } else {
        // ---- epilogue: bias + ReLU -> A_lds, then per-col segment reduce to pooled ----
        __syncthreads();   // all waves done reading T
        #pragma unroll
        for (int nt = 0; nt < 4; ++nt) {
            int c = wn * 64 + nt * 16 + (lane & 15);
            float bias = b2[c];
            #pragma unroll
            for (int mt = 0; mt < 2; ++mt) {
                int rowb = wm * 32 + mt * 16 + ((lane >> 4) << 2);
                #pragma unroll
                for (int r = 0; r < 4; ++r) {
                    float v = fmaxf(acc2[mt][nt][r] + bias, 0.f);
                    A_lds[(rowb + r) * LDT + c] = f2bf(v);
                }
            }
        }
        __syncthreads();
        if (tid < HDIM) {
            int colw = tid;
            int curb = batch_l[0];
            float s = 0.f;
            #pragma unroll 8
            for (int r = 0; r < 64; ++r) {
                int b = batch_l[r];
                if (b != curb) {
                    atomicAdd(&pooled[(long long)curb * HDIM + colw], s);
                    curb = b; s = 0.f;
                }
                s += bf2f(A_lds[r * LDT + colw]);
            }
            atomicAdd(&pooled[(long long)curb * HDIM + colw], s);
        }
    }
}

// ---------------- head ----------------
__global__ __launch_bounds__(64) void fc_head_k(
    const float* __restrict__ pooled,
    const float* __restrict__ w_fc1, const float* __restrict__ b_fc1,
    const float* __restrict__ w_fc2, const float* __restrict__ b_fc2,
    float* __restrict__ out)
{
    int g = blockIdx.x;
    int j = threadIdx.x;   // 0..63
    __shared__ float p[HDIM];
    p[j]      = pooled[(long long)g * HDIM + j];
    p[j + 64] = pooled[(long long)g * HDIM + j + 64];
    __syncthreads();

    float acc = b_fc1[j];
    #pragma unroll 8
    for (int k = 0; k < HDIM; ++k) acc += p[k] * w_fc1[k * 64 + j];
    acc = fmaxf(acc, 0.f);

    float v = acc * w_fc2[j];
    #pragma unroll
    for (int off = 32; off > 0; off >>= 1) v += __shfl_down(v, off, 64);
    if (j == 0) out[g] = v + b_fc2[0];
}

extern "C" void kernel_launch(void* const* d_in, const int* in_sizes, int n_in,
                              void* d_out, int out_size, void* d_ws, size_t ws_size,
                              hipStream_t stream) {
    const float* x     = (const float*)d_in[0];
    const int*   ei    = (const int*)d_in[1];
    const int*   src   = ei;                // edge_index[0]
    const int*   dst   = ei + N_EDGES;      // edge_index[1]
    const int*   batch = (const int*)d_in[3];
    const float* L[3][8];
    for (int l = 0; l < 3; ++l)
        for (int p = 0; p < 8; ++p)
            L[l][p] = (const float*)d_in[4 + 8 * l + p];
    const float* w_fc1 = (const float*)d_in[30];
    const float* b_fc1 = (const float*)d_in[31];
    const float* w_fc2 = (const float*)d_in[32];
    const float* b_fc2 = (const float*)d_in[33];
    float* out = (float*)d_out;

    // ---- workspace layout (bytes) ----
    char* base = (char*)d_ws;
    ushort_t* hA     = (ushort_t*)(base);                 // bf16 [N,128] 51.2 MB
    ushort_t* hB     = (ushort_t*)(base + 51200000);      // bf16 [N,128] 51.2 MB
    ushort_t* xbf    = (ushort_t*)(base + 102400000);     // bf16 [N,32] 12.8 MB
    float*    pooled = (float*)   (base + 115200000);     // f32 [G,128] 5.12 MB
    ushort_t* wpBase = (ushort_t*)(base + 120320000);     // 172 KB
    int*      deg    = (int*)     (base + 120800000);     // 800 KB
    int*      incl   = (int*)     (base + 121600000);     // 800 KB
    int*      bsum   = (int*)     (base + 122400000);     // 4 KB
    int*      rowptr = (int*)     (base + 122404096);     // 800,004 B
    int*      cursor = (int*)     (base + 123204100);     // 800 KB
    int*      colarr = (int*)     (base + 124004100);     // 2.4 MB

    ushort_t* wp1_1 = wpBase;                 // 32*128
    ushort_t* wp2_1 = wp1_1 + 32 * HDIM;
    ushort_t* wp1_2 = wp2_1 + HDIM * HDIM;
    ushort_t* wp2_2 = wp1_2 + HDIM * HDIM;
    ushort_t* wp1_3 = wp2_2 + HDIM * HDIM;
    ushort_t* wp2_3 = wp1_3 + HDIM * HDIM;

    const int GEMM_GRID = N_NODES / 64;          // 3125 (divides exactly)
    const int NB_NODE   = (N_NODES + 255) / 256; // 782
    const int NB_EDGE   = (N_EDGES + 255) / 256; // 2344

    // ---- weight permutes + x convert ----
    permute_w_k<F_NODE><<<(F_NODE * HDIM + 255) / 256, 256, 0, stream>>>(L[0][0], wp1_1);
    permute_w_k<HDIM><<<(HDIM * HDIM + 255) / 256, 256, 0, stream>>>(L[0][6], wp2_1);
    permute_w_k<HDIM><<<(HDIM * HDIM + 255) / 256, 256, 0, stream>>>(L[1][0], wp1_2);
    permute_w_k<HDIM><<<(HDIM * HDIM + 255) / 256, 256, 0, stream>>>(L[1][6], wp2_2);
    permute_w_k<HDIM><<<(HDIM * HDIM + 255) / 256, 256, 0, stream>>>(L[2][0], wp1_3);
    permute_w_k<HDIM><<<(HDIM * HDIM + 255) / 256, 256, 0, stream>>>(L[2][6], wp2_3);
    {
        long long n8 = (long long)N_NODES * F_NODE / 8;
        cvt_bf16_k<<<(int)((n8 + 255) / 256), 256, 0, stream>>>(x, xbf, n8);
    }

    // ---- CSR build ----
    fill_zero_k<<<512, 256, 0, stream>>>((uint_t*)deg, N_NODES);
    hist_k<<<NB_EDGE, 256, 0, stream>>>(dst, deg);
    scan_blocks_k<<<NB_NODE, 256, 0, stream>>>(deg, incl, bsum);
    scan_bsum_k<<<1, 256, 0, stream>>>(bsum, NB_NODE);
    finalize_csr_k<<<NB_NODE, 256, 0, stream>>>(deg, incl, bsum, rowptr, cursor);
    fill_edges_k<<<NB_EDGE, 256, 0, stream>>>(src, dst, cursor, colarr);

    // ---- pooled zero (before layer-3 fused pool) ----
    fill_zero_k<<<512, 256, 0, stream>>>((uint_t*)pooled, (long long)N_GRAPHS * HDIM);

    // ---- 3 fused layers ----
    fused_layer_k<F_NODE, false><<<GEMM_GRID, 256, 0, stream>>>(
        xbf, rowptr, colarr, wp1_1, L[0][1], L[0][2], L[0][3], L[0][4], L[0][5],
        wp2_1, L[0][7], hA, nullptr, nullptr);
    fused_layer_k<HDIM, false><<<GEMM_GRID, 256, 0, stream>>>(
        hA, rowptr, colarr, wp1_2, L[1][1], L[1][2], L[1][3], L[1][4], L[1][5],
        wp2_2, L[1][7], hB, nullptr, nullptr);
    fused_layer_k<HDIM, true><<<GEMM_GRID, 256, 0, stream>>>(
        hB, rowptr, colarr, wp1_3, L[2][1], L[2][2], L[2][3], L[2][4], L[2][5],
        wp2_3, L[2][7], nullptr, batch, pooled);

    // ---- head ----
    fc_head_k<<<N_GRAPHS, 64, 0, stream>>>(pooled, w_fc1, b_fc1, w_fc2, b_fc2, out);
}